// Round 11
// baseline (260.761 us; speedup 1.0000x reference)
//
#include <hip/hip_runtime.h>

#define VOCAB 32000
#define E 64
#define H 8
#define L 25
#define B 1000
#define T 512

#define CHUNK 8                      // timesteps per super-step
#define NCHUNK (T / CHUNK)           // 64
#define NSTEP (NCHUNK + L - 1)       // 88
#define THREADS 256

// Per-layer LDS: 2 parities * CHUNK*8 floats = 128, padded to 132.
// Slot L is a dedicated always-zero dummy read target for layer 0.
#define LAYER_STRIDE 132
#define LDS_FLOATS ((L + 1) * LAYER_STRIDE)   // 3432 floats = 13.7 KB

#define SCALE 2.8853900817779268f    // 2*log2(e): tanh(x)=1-2/(1+exp2(SC*x))

typedef float v2f __attribute__((ext_vector_type(2)));

// ---------------- phase 1: ptab[v][j] = SCALE * (emb[v]·W0[:,j] + bh0[j])
__global__ __launch_bounds__(256) void proj_kernel(
    const float* __restrict__ emb, const float* __restrict__ w0,
    const float* __restrict__ bh, float* __restrict__ ptab)
{
    __shared__ float w0s[E * H];
    int tid = threadIdx.x;
    w0s[tid] = w0[tid];
    w0s[tid + 256] = w0[tid + 256];
    __syncthreads();

    int r = blockIdx.x * 256 + tid;
    if (r >= VOCAB) return;
    const float4* e4 = (const float4*)(emb + r * E);
    const v2f* w2 = (const v2f*)w0s;      // w2[k*4+p] = {W[k][2p], W[k][2p+1]}
    v2f a0 = {0.f, 0.f}, a1 = {0.f, 0.f}, a2 = {0.f, 0.f}, a3 = {0.f, 0.f};
#pragma unroll
    for (int k4 = 0; k4 < E / 4; ++k4) {
        float4 v = e4[k4];
        int kb = k4 * 16;
        a0 += (v2f){v.x, v.x} * w2[kb + 0];  a1 += (v2f){v.x, v.x} * w2[kb + 1];
        a2 += (v2f){v.x, v.x} * w2[kb + 2];  a3 += (v2f){v.x, v.x} * w2[kb + 3];
        a0 += (v2f){v.y, v.y} * w2[kb + 4];  a1 += (v2f){v.y, v.y} * w2[kb + 5];
        a2 += (v2f){v.y, v.y} * w2[kb + 6];  a3 += (v2f){v.y, v.y} * w2[kb + 7];
        a0 += (v2f){v.z, v.z} * w2[kb + 8];  a1 += (v2f){v.z, v.z} * w2[kb + 9];
        a2 += (v2f){v.z, v.z} * w2[kb + 10]; a3 += (v2f){v.z, v.z} * w2[kb + 11];
        a0 += (v2f){v.w, v.w} * w2[kb + 12]; a1 += (v2f){v.w, v.w} * w2[kb + 13];
        a2 += (v2f){v.w, v.w} * w2[kb + 14]; a3 += (v2f){v.w, v.w} * w2[kb + 15];
    }
    float4 b0 = *(const float4*)bh;        // layer-0 bias [0..3]
    float4 b1 = *(const float4*)(bh + 4);  // layer-0 bias [4..7]
    float4* o4 = (float4*)(ptab + r * 8);
    o4[0] = (float4){(a0.x + b0.x) * SCALE, (a0.y + b0.y) * SCALE,
                     (a1.x + b0.z) * SCALE, (a1.y + b0.w) * SCALE};
    o4[1] = (float4){(a2.x + b1.x) * SCALE, (a2.y + b1.y) * SCALE,
                     (a3.x + b1.z) * SCALE, (a3.y + b1.w) * SCALE};
}

// DPP lane exchanges. In lane mapping below, unit-xor{1,2,3} are quad_perm
// and unit-xor4 is lane-xor-8 = ROW_ROR:8. All foldable into VOP2 fmac.
__device__ __forceinline__ float qp1(float x) {    // quad_perm [1,0,3,2]
    return __int_as_float(__builtin_amdgcn_mov_dpp(__float_as_int(x), 0xB1, 0xF, 0xF, true));
}
__device__ __forceinline__ float qp2(float x) {    // quad_perm [2,3,0,1]
    return __int_as_float(__builtin_amdgcn_mov_dpp(__float_as_int(x), 0x4E, 0xF, 0xF, true));
}
__device__ __forceinline__ float qp3(float x) {    // quad_perm [3,2,1,0]
    return __int_as_float(__builtin_amdgcn_mov_dpp(__float_as_int(x), 0x1B, 0xF, 0xF, true));
}
__device__ __forceinline__ float ror8(float x) {   // ROW_ROR:8 == lane^8 in row
    return __int_as_float(__builtin_amdgcn_mov_dpp(__float_as_int(x), 0x128, 0xF, 0xF, true));
}

// ---------------- phase 2: layer-pipelined recurrence, DPP-fma dot products.
// Lane mapping: row = tid>>4; unit j at pos (j&3)+((j>>2)<<3)+(g&1)*4;
// layer g = 2*row + ((pos>>2)&1). Each lane accumulates its own output j:
// acc_j = sum_m W[j^m][j] * v_{j^m}, with v_{j^m} fetched via DPP.
__global__ __launch_bounds__(THREADS) void rnn_recur(
    const int*   __restrict__ x,      // [B,T]
    const float* __restrict__ h0,     // [L,B,H]
    const float* __restrict__ wrest,  // [L-1,H,H]
    const float* __restrict__ whh_g,  // [L,H,H]
    const float* __restrict__ bh,     // [L,H]
    const float* __restrict__ why,    // [H]
    const float* __restrict__ by,     // [1]
    const float* __restrict__ ptab,   // [VOCAB,H] pre-scaled+biased
    float*       __restrict__ out)    // [B] logits ++ [L,B,H] h_last
{
    __shared__ __align__(16) float buf[LDS_FLOATS];

    const int tid = threadIdx.x;
    // zero-init: dummy slot (layer-0 input reads) must be 0
    for (int k = tid; k < LDS_FLOATS; k += THREADS) buf[k] = 0.f;

    const int row = tid >> 4;
    const int lp  = tid & 15;
    const int j   = (lp & 3) | ((lp >> 3) << 2);   // unit
    const int g   = row * 2 + ((lp >> 2) & 1);     // layer
    const bool active = g < L;
    const int gc  = active ? g : 0;
    const int b = blockIdx.x;

    float wh[8], wx[8];
    float h = 0.f, hr = 0.f;
    float pv[CHUNK];
#pragma unroll
    for (int m = 0; m < 8; ++m) { wh[m] = 0.f; wx[m] = 0.f; }

    float* mybuf = &buf[gc * LAYER_STRIDE];
    const float* prevbuf = (gc > 0) ? (mybuf - LAYER_STRIDE)
                                    : (&buf[L * LAYER_STRIDE]);   // zero dummy

    if (active) {
        const float* whL = whh_g + g * 64;
#pragma unroll
        for (int m = 0; m < 8; ++m)
            wh[m] = whL[(j ^ m) * 8 + j] * SCALE;
        if (g > 0) {
            const float* wxL = wrest + (g - 1) * 64;
#pragma unroll
            for (int m = 0; m < 8; ++m)
                wx[m] = wxL[(j ^ m) * 8 + j] * SCALE;
        }
        h = h0[(g * B + b) * H + j];
        float bs = bh[g * 8 + j] * SCALE;      // scaled bias (g>0 path)
#pragma unroll
        for (int ct = 0; ct < CHUNK; ++ct) pv[ct] = bs;
    }
    hr = ror8(h);

    const int xbase = b * T;
    if (active && g == 0) {
#pragma unroll
        for (int ct = 0; ct < CHUNK; ++ct)
            pv[ct] = ptab[x[xbase + ct] * H + j];   // pre-scaled, biased
    }
    __syncthreads();

    for (int s = 0; s < NSTEP; ++s) {
        const int c = s - g;
        if (active && (unsigned)c < (unsigned)NCHUNK) {
            const int p = c & 1;
            float* wptr = mybuf + p * (CHUNK * 8);
            const float* rptr = prevbuf + p * (CHUNK * 8);

            int4 t0, t1;                       // next-chunk tokens (layer 0)
            const bool pf = (g == 0) && (c + 1 < NCHUNK);
            if (pf) {
                const int4* xp4 = (const int4*)(x + xbase + (c + 1) * CHUNK);
                t0 = xp4[0];
                t1 = xp4[1];
            }

            // ---- phase A: own-unit input loads + x-dots (parallel, high ILP)
            float xin[CHUNK];
#pragma unroll
            for (int ct = 0; ct < CHUNK; ++ct)
                xin[ct] = rptr[ct * 8 + j];

            float xa[CHUNK];
#pragma unroll
            for (int ct = 0; ct < CHUNK; ++ct) {
                float v  = xin[ct];
                float vr = ror8(v);
                float a0 = pv[ct];
                a0 = __builtin_fmaf(v,       wx[0], a0);
                float a1 = qp1(v) * wx[1];
                a0 = __builtin_fmaf(qp2(v),  wx[2], a0);
                a1 = __builtin_fmaf(qp3(v),  wx[3], a1);
                a0 = __builtin_fmaf(vr,      wx[4], a0);
                a1 = __builtin_fmaf(qp1(vr), wx[5], a1);
                a0 = __builtin_fmaf(qp2(vr), wx[6], a0);
                a1 = __builtin_fmaf(qp3(vr), wx[7], a1);
                xa[ct] = a0 + a1;
            }

            // ---- phase B: serial h-chain
#pragma unroll
            for (int ct = 0; ct < CHUNK; ++ct) {
                float b0 = xa[ct];
                b0 = __builtin_fmaf(h,       wh[0], b0);
                float b1 = qp1(h) * wh[1];
                b0 = __builtin_fmaf(qp2(h),  wh[2], b0);
                b1 = __builtin_fmaf(qp3(h),  wh[3], b1);
                b0 = __builtin_fmaf(hr,      wh[4], b0);
                b1 = __builtin_fmaf(qp1(hr), wh[5], b1);
                b0 = __builtin_fmaf(qp2(hr), wh[6], b0);
                b1 = __builtin_fmaf(qp3(hr), wh[7], b1);
                float arg = b0 + b1;                      // pre-scaled
                float tt = __builtin_amdgcn_exp2f(arg);
                float rc = __builtin_amdgcn_rcpf(1.0f + tt);
                float hn = __builtin_fmaf(-2.0f, rc, 1.0f);

                wptr[ct * 8 + j] = hn;         // cross-layer handoff
                h  = hn;
                hr = ror8(hn);
            }

            if (pf) {
                pv[0] = ptab[t0.x * H + j];
                pv[1] = ptab[t0.y * H + j];
                pv[2] = ptab[t0.z * H + j];
                pv[3] = ptab[t0.w * H + j];
                pv[4] = ptab[t1.x * H + j];
                pv[5] = ptab[t1.y * H + j];
                pv[6] = ptab[t1.z * H + j];
                pv[7] = ptab[t1.w * H + j];
            }

            if (c == NCHUNK - 1) {
                out[B + (g * B + b) * H + j] = h;       // h_last
                if (g == L - 1) {                       // logits: 8-lane reduce
                    float v = h * why[j];
                    v += qp1(v);
                    v += qp2(v);
                    v += ror8(v);
                    if (j == 0) out[b] = v + by[0];
                }
            }
        }
        __syncthreads();
    }
}

extern "C" void kernel_launch(void* const* d_in, const int* in_sizes, int n_in,
                              void* d_out, int out_size, void* d_ws, size_t ws_size,
                              hipStream_t stream) {
    const int*   x     = (const int*)d_in[0];
    const float* h0    = (const float*)d_in[1];
    const float* emb   = (const float*)d_in[2];
    const float* w0    = (const float*)d_in[3];
    const float* wrest = (const float*)d_in[4];
    const float* whh   = (const float*)d_in[5];
    const float* bh    = (const float*)d_in[6];
    const float* why   = (const float*)d_in[7];
    const float* by    = (const float*)d_in[8];
    float* out  = (float*)d_out;
    float* ptab = (float*)d_ws;                       // 1 MB scratch

    hipLaunchKernelGGL(proj_kernel, dim3((VOCAB + 255) / 256), dim3(256),
                       0, stream, emb, w0, bh, ptab);
    hipLaunchKernelGGL(rnn_recur, dim3(B), dim3(THREADS),
                       0, stream, x, h0, wrest, whh, bh, why, by, ptab, out);
}

// Round 12
// 222.720 us; speedup vs baseline: 1.1708x; 1.1708x over previous
//
#include <hip/hip_runtime.h>

#define VOCAB 32000
#define E 64
#define H 8
#define L 25
#define B 1000
#define T 512

#define CHUNK 8                      // timesteps per super-step
#define NCHUNK (T / CHUNK)           // 64
#define NSTEP (NCHUNK + L - 1)       // 88
#define THREADS 256

// Per-layer LDS: 2 parities * CHUNK*8 floats = 128, padded to 132.
// Slot L is a dedicated always-zero dummy read target for layer 0.
#define LAYER_STRIDE 132
#define LDS_FLOATS ((L + 1) * LAYER_STRIDE)   // 3432 floats = 13.7 KB

#define SCALE 2.8853900817779268f    // 2*log2(e): tanh(x)=1-2/(1+exp2(SC*x))

typedef float v2f __attribute__((ext_vector_type(2)));
typedef float v4f __attribute__((ext_vector_type(4)));

// Guaranteed packed fp32 (VOP3P, full-rate on CDNA): plain mnemonic =
// elementwise lo/hi, no op_sel modifiers.
__device__ __forceinline__ v2f pk_fma(v2f a, v2f b, v2f c) {
    v2f d;
    asm("v_pk_fma_f32 %0, %1, %2, %3" : "=v"(d) : "v"(a), "v"(b), "v"(c));
    return d;
}
__device__ __forceinline__ v2f pk_mul(v2f a, v2f b) {
    v2f d;
    asm("v_pk_mul_f32 %0, %1, %2" : "=v"(d) : "v"(a), "v"(b));
    return d;
}
__device__ __forceinline__ v2f pk_add(v2f a, v2f b) {
    v2f d;
    asm("v_pk_add_f32 %0, %1, %2" : "=v"(d) : "v"(a), "v"(b));
    return d;
}

// ---------------- phase 1: ptab[v][j] = SCALE * (emb[v]·W0[:,j] + bh0[j])
__global__ __launch_bounds__(256) void proj_kernel(
    const float* __restrict__ emb, const float* __restrict__ w0,
    const float* __restrict__ bh, float* __restrict__ ptab)
{
    __shared__ float w0s[E * H];
    int tid = threadIdx.x;
    w0s[tid] = w0[tid];
    w0s[tid + 256] = w0[tid + 256];
    __syncthreads();

    int r = blockIdx.x * 256 + tid;
    if (r >= VOCAB) return;
    const float4* e4 = (const float4*)(emb + r * E);
    const v2f* w2 = (const v2f*)w0s;      // w2[k*4+p] = {W[k][2p], W[k][2p+1]}
    v2f a0 = {0.f, 0.f}, a1 = {0.f, 0.f}, a2 = {0.f, 0.f}, a3 = {0.f, 0.f};
#pragma unroll
    for (int k4 = 0; k4 < E / 4; ++k4) {
        float4 v = e4[k4];
        int kb = k4 * 16;
        a0 = pk_fma((v2f){v.x, v.x}, w2[kb + 0], a0);
        a1 = pk_fma((v2f){v.x, v.x}, w2[kb + 1], a1);
        a2 = pk_fma((v2f){v.x, v.x}, w2[kb + 2], a2);
        a3 = pk_fma((v2f){v.x, v.x}, w2[kb + 3], a3);
        a0 = pk_fma((v2f){v.y, v.y}, w2[kb + 4], a0);
        a1 = pk_fma((v2f){v.y, v.y}, w2[kb + 5], a1);
        a2 = pk_fma((v2f){v.y, v.y}, w2[kb + 6], a2);
        a3 = pk_fma((v2f){v.y, v.y}, w2[kb + 7], a3);
        a0 = pk_fma((v2f){v.z, v.z}, w2[kb + 8], a0);
        a1 = pk_fma((v2f){v.z, v.z}, w2[kb + 9], a1);
        a2 = pk_fma((v2f){v.z, v.z}, w2[kb + 10], a2);
        a3 = pk_fma((v2f){v.z, v.z}, w2[kb + 11], a3);
        a0 = pk_fma((v2f){v.w, v.w}, w2[kb + 12], a0);
        a1 = pk_fma((v2f){v.w, v.w}, w2[kb + 13], a1);
        a2 = pk_fma((v2f){v.w, v.w}, w2[kb + 14], a2);
        a3 = pk_fma((v2f){v.w, v.w}, w2[kb + 15], a3);
    }
    float4 b0 = *(const float4*)bh;        // layer-0 bias [0..3]
    float4 b1 = *(const float4*)(bh + 4);  // layer-0 bias [4..7]
    float4* o4 = (float4*)(ptab + r * 8);
    o4[0] = (float4){(a0.x + b0.x) * SCALE, (a0.y + b0.y) * SCALE,
                     (a1.x + b0.z) * SCALE, (a1.y + b0.w) * SCALE};
    o4[1] = (float4){(a2.x + b1.x) * SCALE, (a2.y + b1.y) * SCALE,
                     (a3.x + b1.z) * SCALE, (a3.y + b1.w) * SCALE};
}

// DPP exchanges (HW-verified R4-R9): unit-xor1/2 = quad_perm, unit-xor4 =
// lane-xor-8 = ROW_ROR:8 within a 16-lane row.
__device__ __forceinline__ float qp1(float x) {    // quad_perm [1,0,3,2]
    return __int_as_float(__builtin_amdgcn_mov_dpp(__float_as_int(x), 0xB1, 0xF, 0xF, true));
}
__device__ __forceinline__ float qp2(float x) {    // quad_perm [2,3,0,1]
    return __int_as_float(__builtin_amdgcn_mov_dpp(__float_as_int(x), 0x4E, 0xF, 0xF, true));
}
__device__ __forceinline__ float ror8(float x) {   // ROW_ROR:8 == lane^8 in row
    return __int_as_float(__builtin_amdgcn_mov_dpp(__float_as_int(x), 0x128, 0xF, 0xF, true));
}

// ---------------- phase 2: layer-pipelined recurrence (R9 structure),
// dots forced to v_pk_fma_f32. Lane mapping: row=tid>>4; unit j at
// pos (j&3)+((j>>2)<<3)+(g&1)*4; layer g = 2*row + ((pos>>2)&1).
__global__ __launch_bounds__(THREADS) void rnn_recur(
    const int*   __restrict__ x,      // [B,T]
    const float* __restrict__ h0,     // [L,B,H]
    const float* __restrict__ wrest,  // [L-1,H,H]
    const float* __restrict__ whh_g,  // [L,H,H]
    const float* __restrict__ bh,     // [L,H]
    const float* __restrict__ why,    // [H]
    const float* __restrict__ by,     // [1]
    const float* __restrict__ ptab,   // [VOCAB,H] pre-scaled+biased
    float*       __restrict__ out)    // [B] logits ++ [L,B,H] h_last
{
    __shared__ __align__(16) float buf[LDS_FLOATS];

    const int tid = threadIdx.x;
    // zero-init: dummy slot (layer-0 input reads) must be 0
    for (int k = tid; k < LDS_FLOATS; k += THREADS) buf[k] = 0.f;

    const int row = tid >> 4;
    const int lp  = tid & 15;
    const int j   = (lp & 3) | ((lp >> 3) << 2);   // unit
    const int g   = row * 2 + ((lp >> 2) & 1);     // layer
    const bool active = g < L;
    const int gc  = active ? g : 0;
    const int b = blockIdx.x;

    v2f wh01 = {0.f, 0.f}, wh23 = {0.f, 0.f}, wh45 = {0.f, 0.f}, wh67 = {0.f, 0.f};
    v2f wx01 = {0.f, 0.f}, wx23 = {0.f, 0.f}, wx45 = {0.f, 0.f}, wx67 = {0.f, 0.f};
    v2f h01  = {0.f, 0.f}, h23  = {0.f, 0.f}, h45  = {0.f, 0.f}, h67  = {0.f, 0.f};
    float pv[CHUNK];

    float* mybuf = &buf[gc * LAYER_STRIDE];
    const float* prevbuf = (gc > 0) ? (mybuf - LAYER_STRIDE)
                                    : (&buf[L * LAYER_STRIDE]);   // zero dummy

    if (active) {
        const float* whL = whh_g + g * 64;
        wh01 = (v2f){whL[(j ^ 0) * 8 + j], whL[(j ^ 1) * 8 + j]} * SCALE;
        wh23 = (v2f){whL[(j ^ 2) * 8 + j], whL[(j ^ 3) * 8 + j]} * SCALE;
        wh45 = (v2f){whL[(j ^ 4) * 8 + j], whL[(j ^ 5) * 8 + j]} * SCALE;
        wh67 = (v2f){whL[(j ^ 6) * 8 + j], whL[(j ^ 7) * 8 + j]} * SCALE;
        if (g > 0) {
            const float* wxL = wrest + (g - 1) * 64;
            wx01 = (v2f){wxL[0 * 8 + j], wxL[1 * 8 + j]} * SCALE;
            wx23 = (v2f){wxL[2 * 8 + j], wxL[3 * 8 + j]} * SCALE;
            wx45 = (v2f){wxL[4 * 8 + j], wxL[5 * 8 + j]} * SCALE;
            wx67 = (v2f){wxL[6 * 8 + j], wxL[7 * 8 + j]} * SCALE;
        }
        const float* h0p = h0 + (g * B + b) * H;
        h01 = (v2f){h0p[j ^ 0], h0p[j ^ 1]};
        h23 = (v2f){h0p[j ^ 2], h0p[j ^ 3]};
        h45 = (v2f){h0p[j ^ 4], h0p[j ^ 5]};
        h67 = (v2f){h0p[j ^ 6], h0p[j ^ 7]};
        float bs = bh[g * 8 + j] * SCALE;    // scaled bias (g>0 path)
#pragma unroll
        for (int ct = 0; ct < CHUNK; ++ct) pv[ct] = bs;
    }

    const int xbase = b * T;
    if (active && g == 0) {
#pragma unroll
        for (int ct = 0; ct < CHUNK; ++ct)
            pv[ct] = ptab[x[xbase + ct] * H + j];   // pre-scaled, biased
    }
    __syncthreads();

    for (int s = 0; s < NSTEP; ++s) {
        const int c = s - g;
        if (active && (unsigned)c < (unsigned)NCHUNK) {
            const int p = c & 1;
            float* wptr = mybuf + p * (CHUNK * 8);
            const v4f* ip4 = (const v4f*)(prevbuf + p * (CHUNK * 8));

            int4 t0, t1;                       // next-chunk tokens (layer 0)
            const bool pf = (g == 0) && (c + 1 < NCHUNK);
            if (pf) {
                const int4* xp4 = (const int4*)(x + xbase + (c + 1) * CHUNK);
                t0 = xp4[0];
                t1 = xp4[1];
            }

            v4f ia = ip4[0], ib = ip4[1];
#pragma unroll
            for (int ct = 0; ct < CHUNK; ++ct) {
                v4f ian = ia, ibn = ib;
                if (ct < CHUNK - 1) {          // read-ahead (before this ct's write)
                    ian = ip4[2 * ct + 2];
                    ibn = ip4[2 * ct + 3];
                }
                v2f i01 = __builtin_shufflevector(ia, ia, 0, 1);
                v2f i23 = __builtin_shufflevector(ia, ia, 2, 3);
                v2f i45 = __builtin_shufflevector(ib, ib, 0, 1);
                v2f i67 = __builtin_shufflevector(ib, ib, 2, 3);

                v2f acc0 = pk_mul(i01, wx01);
                v2f acc1 = pk_mul(i23, wx23);
                acc0 = pk_fma(i45, wx45, acc0);
                acc1 = pk_fma(i67, wx67, acc1);
                acc0 = pk_fma(h01, wh01, acc0);
                acc1 = pk_fma(h23, wh23, acc1);
                acc0 = pk_fma(h45, wh45, acc0);
                acc1 = pk_fma(h67, wh67, acc1);
                acc0 = pk_add(acc0, acc1);
                float arg = acc0.x + acc0.y + pv[ct];   // pre-scaled
                float tt = __builtin_amdgcn_exp2f(arg);
                float rc = __builtin_amdgcn_rcpf(1.0f + tt);
                float hn = __builtin_fmaf(-2.0f, rc, 1.0f);

                wptr[ct * 8 + j] = hn;         // cross-layer handoff

                float o1 = qp1(hn);
                float q0 = qp2(hn);
                float q1 = qp2(o1);
                h01 = (v2f){hn, o1};
                h23 = (v2f){q0, q1};
                h45 = (v2f){ror8(hn), ror8(o1)};
                h67 = (v2f){ror8(q0), ror8(q1)};

                ia = ian;
                ib = ibn;
            }

            if (pf) {
                pv[0] = ptab[t0.x * H + j];
                pv[1] = ptab[t0.y * H + j];
                pv[2] = ptab[t0.z * H + j];
                pv[3] = ptab[t0.w * H + j];
                pv[4] = ptab[t1.x * H + j];
                pv[5] = ptab[t1.y * H + j];
                pv[6] = ptab[t1.z * H + j];
                pv[7] = ptab[t1.w * H + j];
            }

            if (c == NCHUNK - 1) {
                out[B + (g * B + b) * H + j] = h01.x;   // h_last
                if (g == L - 1) {                       // logits: 8-lane reduce
                    float v = h01.x * why[j];
                    v += qp1(v);
                    v += qp2(v);
                    v += ror8(v);
                    if (j == 0) out[b] = v + by[0];
                }
            }
        }
        __syncthreads();
    }
}

extern "C" void kernel_launch(void* const* d_in, const int* in_sizes, int n_in,
                              void* d_out, int out_size, void* d_ws, size_t ws_size,
                              hipStream_t stream) {
    const int*   x     = (const int*)d_in[0];
    const float* h0    = (const float*)d_in[1];
    const float* emb   = (const float*)d_in[2];
    const float* w0    = (const float*)d_in[3];
    const float* wrest = (const float*)d_in[4];
    const float* whh   = (const float*)d_in[5];
    const float* bh    = (const float*)d_in[6];
    const float* why   = (const float*)d_in[7];
    const float* by    = (const float*)d_in[8];
    float* out  = (float*)d_out;
    float* ptab = (float*)d_ws;                       // 1 MB scratch

    hipLaunchKernelGGL(proj_kernel, dim3((VOCAB + 255) / 256), dim3(256),
                       0, stream, emb, w0, bh, ptab);
    hipLaunchKernelGGL(rnn_recur, dim3(B), dim3(THREADS),
                       0, stream, x, h0, wrest, whh, bh, why, by, ptab, out);
}

// Round 13
// 222.451 us; speedup vs baseline: 1.1722x; 1.0012x over previous
//
#include <hip/hip_runtime.h>

#define VOCAB 32000
#define E 64
#define H 8
#define L 25
#define B 1000
#define T 512

#define CHUNK 8                      // timesteps per super-step
#define NCHUNK (T / CHUNK)           // 64
#define NSTEP (NCHUNK + L - 1)       // 88
#define THREADS 256

// Per-layer LDS: 2 parities * CHUNK*8 floats = 128, padded to 132.
// Slot L is a dedicated always-zero dummy read target for layer 0.
#define LAYER_STRIDE 132
#define LDS_FLOATS ((L + 1) * LAYER_STRIDE)   // 3432 floats = 13.7 KB

#define SCALE 2.8853900817779268f    // 2*log2(e): tanh(x)=1-2/(1+exp2(SC*x))

typedef float v2f __attribute__((ext_vector_type(2)));
typedef float v4f __attribute__((ext_vector_type(4)));

// Guaranteed packed fp32 (VOP3P): plain mnemonic = elementwise lo/hi.
__device__ __forceinline__ v2f pk_fma(v2f a, v2f b, v2f c) {
    v2f d;
    asm("v_pk_fma_f32 %0, %1, %2, %3" : "=v"(d) : "v"(a), "v"(b), "v"(c));
    return d;
}
__device__ __forceinline__ v2f pk_mul(v2f a, v2f b) {
    v2f d;
    asm("v_pk_mul_f32 %0, %1, %2" : "=v"(d) : "v"(a), "v"(b));
    return d;
}
__device__ __forceinline__ v2f pk_add(v2f a, v2f b) {
    v2f d;
    asm("v_pk_add_f32 %0, %1, %2" : "=v"(d) : "v"(a), "v"(b));
    return d;
}

// ---------------- phase 1: ptab[v][j] = SCALE * (emb[v]·W0[:,j] + bh0[j])
// Coalesced: block stages 32 emb rows via contiguous float4 loads into
// padded LDS (stride 65 -> conflict-free broadcast), then thread-per-(row,j).
#define PROJ_ROWS 32
#define ESTRIDE 65
__global__ __launch_bounds__(256) void proj_kernel(
    const float* __restrict__ emb, const float* __restrict__ w0,
    const float* __restrict__ bh, float* __restrict__ ptab)
{
    __shared__ float es[PROJ_ROWS * ESTRIDE];   // 2080 floats
    __shared__ float w0s[E * H];                // 512 floats

    const int tid = threadIdx.x;
    w0s[tid] = w0[tid];
    w0s[tid + 256] = w0[tid + 256];

    // stage 32 rows x 64 floats = 512 float4, 2 per thread, fully coalesced
    const float4* e4 = (const float4*)(emb) + (size_t)blockIdx.x * (PROJ_ROWS * E / 4);
#pragma unroll
    for (int it = 0; it < 2; ++it) {
        int idx = tid + it * 256;          // 0..511
        float4 v = e4[idx];
        int r  = idx >> 4;                 // row 0..31
        int k0 = (idx & 15) * 4;           // col 0,4,..,60
        float* d = &es[r * ESTRIDE + k0];
        d[0] = v.x; d[1] = v.y; d[2] = v.z; d[3] = v.w;
    }
    __syncthreads();

    const int r = tid >> 3;                // row 0..31
    const int j = tid & 7;                 // unit
    const float* e = &es[r * ESTRIDE];
    float a0 = 0.f, a1 = 0.f, a2 = 0.f, a3 = 0.f;
#pragma unroll
    for (int k = 0; k < E; k += 4) {
        a0 = __builtin_fmaf(e[k + 0], w0s[(k + 0) * H + j], a0);
        a1 = __builtin_fmaf(e[k + 1], w0s[(k + 1) * H + j], a1);
        a2 = __builtin_fmaf(e[k + 2], w0s[(k + 2) * H + j], a2);
        a3 = __builtin_fmaf(e[k + 3], w0s[(k + 3) * H + j], a3);
    }
    float dot = (a0 + a1) + (a2 + a3);
    int row = blockIdx.x * PROJ_ROWS + r;
    ptab[row * H + j] = (dot + bh[j]) * SCALE;   // pre-scaled + biased
}

// DPP exchanges (HW-verified R4-R12): unit-xor1/2 = quad_perm, unit-xor4 =
// lane-xor-8 = ROW_ROR:8 within a 16-lane row.
__device__ __forceinline__ float qp1(float x) {    // quad_perm [1,0,3,2]
    return __int_as_float(__builtin_amdgcn_mov_dpp(__float_as_int(x), 0xB1, 0xF, 0xF, true));
}
__device__ __forceinline__ float qp2(float x) {    // quad_perm [2,3,0,1]
    return __int_as_float(__builtin_amdgcn_mov_dpp(__float_as_int(x), 0x4E, 0xF, 0xF, true));
}
__device__ __forceinline__ float ror8(float x) {   // ROW_ROR:8 == lane^8 in row
    return __int_as_float(__builtin_amdgcn_mov_dpp(__float_as_int(x), 0x128, 0xF, 0xF, true));
}

// ---------------- phase 2: layer-pipelined recurrence (R12, measured best).
// Lane mapping: row=tid>>4; unit j at pos (j&3)+((j>>2)<<3)+(g&1)*4;
// layer g = 2*row + ((pos>>2)&1). Branchless; weights pre-scaled by SCALE.
__global__ __launch_bounds__(THREADS) void rnn_recur(
    const int*   __restrict__ x,      // [B,T]
    const float* __restrict__ h0,     // [L,B,H]
    const float* __restrict__ wrest,  // [L-1,H,H]
    const float* __restrict__ whh_g,  // [L,H,H]
    const float* __restrict__ bh,     // [L,H]
    const float* __restrict__ why,    // [H]
    const float* __restrict__ by,     // [1]
    const float* __restrict__ ptab,   // [VOCAB,H] pre-scaled+biased
    float*       __restrict__ out)    // [B] logits ++ [L,B,H] h_last
{
    __shared__ __align__(16) float buf[LDS_FLOATS];

    const int tid = threadIdx.x;
    // zero-init: dummy slot (layer-0 input reads) must be 0
    for (int k = tid; k < LDS_FLOATS; k += THREADS) buf[k] = 0.f;

    const int row = tid >> 4;
    const int lp  = tid & 15;
    const int j   = (lp & 3) | ((lp >> 3) << 2);   // unit
    const int g   = row * 2 + ((lp >> 2) & 1);     // layer
    const bool active = g < L;
    const int gc  = active ? g : 0;
    const int b = blockIdx.x;

    v2f wh01 = {0.f, 0.f}, wh23 = {0.f, 0.f}, wh45 = {0.f, 0.f}, wh67 = {0.f, 0.f};
    v2f wx01 = {0.f, 0.f}, wx23 = {0.f, 0.f}, wx45 = {0.f, 0.f}, wx67 = {0.f, 0.f};
    v2f h01  = {0.f, 0.f}, h23  = {0.f, 0.f}, h45  = {0.f, 0.f}, h67  = {0.f, 0.f};
    float pv[CHUNK];

    float* mybuf = &buf[gc * LAYER_STRIDE];
    const float* prevbuf = (gc > 0) ? (mybuf - LAYER_STRIDE)
                                    : (&buf[L * LAYER_STRIDE]);   // zero dummy

    if (active) {
        const float* whL = whh_g + g * 64;
        wh01 = (v2f){whL[(j ^ 0) * 8 + j], whL[(j ^ 1) * 8 + j]} * SCALE;
        wh23 = (v2f){whL[(j ^ 2) * 8 + j], whL[(j ^ 3) * 8 + j]} * SCALE;
        wh45 = (v2f){whL[(j ^ 4) * 8 + j], whL[(j ^ 5) * 8 + j]} * SCALE;
        wh67 = (v2f){whL[(j ^ 6) * 8 + j], whL[(j ^ 7) * 8 + j]} * SCALE;
        if (g > 0) {
            const float* wxL = wrest + (g - 1) * 64;
            wx01 = (v2f){wxL[0 * 8 + j], wxL[1 * 8 + j]} * SCALE;
            wx23 = (v2f){wxL[2 * 8 + j], wxL[3 * 8 + j]} * SCALE;
            wx45 = (v2f){wxL[4 * 8 + j], wxL[5 * 8 + j]} * SCALE;
            wx67 = (v2f){wxL[6 * 8 + j], wxL[7 * 8 + j]} * SCALE;
        }
        const float* h0p = h0 + (g * B + b) * H;
        h01 = (v2f){h0p[j ^ 0], h0p[j ^ 1]};
        h23 = (v2f){h0p[j ^ 2], h0p[j ^ 3]};
        h45 = (v2f){h0p[j ^ 4], h0p[j ^ 5]};
        h67 = (v2f){h0p[j ^ 6], h0p[j ^ 7]};
        float bs = bh[g * 8 + j] * SCALE;    // scaled bias (g>0 path)
#pragma unroll
        for (int ct = 0; ct < CHUNK; ++ct) pv[ct] = bs;
    }

    const int xbase = b * T;
    if (active && g == 0) {
#pragma unroll
        for (int ct = 0; ct < CHUNK; ++ct)
            pv[ct] = ptab[x[xbase + ct] * H + j];   // pre-scaled, biased
    }
    __syncthreads();

    for (int s = 0; s < NSTEP; ++s) {
        const int c = s - g;
        if (active && (unsigned)c < (unsigned)NCHUNK) {
            const int p = c & 1;
            float* wptr = mybuf + p * (CHUNK * 8);
            const v4f* ip4 = (const v4f*)(prevbuf + p * (CHUNK * 8));

            int4 t0, t1;                       // next-chunk tokens (layer 0)
            const bool pf = (g == 0) && (c + 1 < NCHUNK);
            if (pf) {
                const int4* xp4 = (const int4*)(x + xbase + (c + 1) * CHUNK);
                t0 = xp4[0];
                t1 = xp4[1];
            }

            v4f ia = ip4[0], ib = ip4[1];
#pragma unroll
            for (int ct = 0; ct < CHUNK; ++ct) {
                v4f ian = ia, ibn = ib;
                if (ct < CHUNK - 1) {          // read-ahead (before this ct's write)
                    ian = ip4[2 * ct + 2];
                    ibn = ip4[2 * ct + 3];
                }
                v2f i01 = __builtin_shufflevector(ia, ia, 0, 1);
                v2f i23 = __builtin_shufflevector(ia, ia, 2, 3);
                v2f i45 = __builtin_shufflevector(ib, ib, 0, 1);
                v2f i67 = __builtin_shufflevector(ib, ib, 2, 3);

                v2f acc0 = pk_mul(i01, wx01);
                v2f acc1 = pk_mul(i23, wx23);
                acc0 = pk_fma(i45, wx45, acc0);
                acc1 = pk_fma(i67, wx67, acc1);
                acc0 = pk_fma(h01, wh01, acc0);
                acc1 = pk_fma(h23, wh23, acc1);
                acc0 = pk_fma(h45, wh45, acc0);
                acc1 = pk_fma(h67, wh67, acc1);
                acc0 = pk_add(acc0, acc1);
                float arg = acc0.x + acc0.y + pv[ct];   // pre-scaled
                float tt = __builtin_amdgcn_exp2f(arg);
                float rc = __builtin_amdgcn_rcpf(1.0f + tt);
                float hn = __builtin_fmaf(-2.0f, rc, 1.0f);

                wptr[ct * 8 + j] = hn;         // cross-layer handoff

                float o1 = qp1(hn);
                float q0 = qp2(hn);
                float q1 = qp2(o1);
                h01 = (v2f){hn, o1};
                h23 = (v2f){q0, q1};
                h45 = (v2f){ror8(hn), ror8(o1)};
                h67 = (v2f){ror8(q0), ror8(q1)};

                ia = ian;
                ib = ibn;
            }

            if (pf) {
                pv[0] = ptab[t0.x * H + j];
                pv[1] = ptab[t0.y * H + j];
                pv[2] = ptab[t0.z * H + j];
                pv[3] = ptab[t0.w * H + j];
                pv[4] = ptab[t1.x * H + j];
                pv[5] = ptab[t1.y * H + j];
                pv[6] = ptab[t1.z * H + j];
                pv[7] = ptab[t1.w * H + j];
            }

            if (c == NCHUNK - 1) {
                out[B + (g * B + b) * H + j] = h01.x;   // h_last
                if (g == L - 1) {                       // logits: 8-lane reduce
                    float v = h01.x * why[j];
                    v += qp1(v);
                    v += qp2(v);
                    v += ror8(v);
                    if (j == 0) out[b] = v + by[0];
                }
            }
        }
        __syncthreads();
    }
}

extern "C" void kernel_launch(void* const* d_in, const int* in_sizes, int n_in,
                              void* d_out, int out_size, void* d_ws, size_t ws_size,
                              hipStream_t stream) {
    const int*   x     = (const int*)d_in[0];
    const float* h0    = (const float*)d_in[1];
    const float* emb   = (const float*)d_in[2];
    const float* w0    = (const float*)d_in[3];
    const float* wrest = (const float*)d_in[4];
    const float* whh   = (const float*)d_in[5];
    const float* bh    = (const float*)d_in[6];
    const float* why   = (const float*)d_in[7];
    const float* by    = (const float*)d_in[8];
    float* out  = (float*)d_out;
    float* ptab = (float*)d_ws;                       // 1 MB scratch

    hipLaunchKernelGGL(proj_kernel, dim3(VOCAB / PROJ_ROWS), dim3(256),
                       0, stream, emb, w0, bh, ptab);
    hipLaunchKernelGGL(rnn_recur, dim3(B), dim3(THREADS),
                       0, stream, x, h0, wrest, whh, bh, why, by, ptab, out);
}